// Round 12
// baseline (22.715 us; speedup 1.0000x reference)
//
#include <hip/hip_runtime.h>
#include <math.h>

#define NUM_HEADS 16
#define DIM_HID 64
#define NUM_GAUSS 251
#define W_SCA_COLS 320   // DIM_HID + 256
#define GP 20            // padded stride (floats): 80B, 16B-aligned
#define RAD 0.14f        // window radius: excluded terms < exp(-6.125)*|w| ~ 5e-4
#define NW 8             // fixed window iterations
#define TPB 256
#define CHUNK 256        // edges per chunk
#define NBLK 264         // persistent blocks; each handles ceil(782/264)=3 chunks

// native vector type for nontemporal builtins (HIP float4 is a class -> rejected)
typedef float f4 __attribute__((ext_vector_type(4)));

struct F3 { float x, y, z; };

// ---------------------------------------------------------------------------
// r12: grid-stride persistent blocks + 2-stage chunk prefetch pipeline.
// Evidence: 1563-block variants (r4,r8) cost +7us vs 782-block (r5,r9) ->
// per-block prologue ~2.2us (16-deep staging load chain + fold + 2 barriers).
// Fix: 264 blocks x 3 chunks (prologue generations 3.05 -> 1), staging via
// 4x independent float4 (1 round trip), idx/feat prefetched 2 chunks ahead,
// pos gathered 1 chunk ahead under current chunk's gate compute.
// Keep (proven): NT loads/stores (r11 +2.4us), LDS-transpose stores, fixed-8
// window, wave-uniform s_load gate weights.
//
// Algebraic collapse validated r2-r11 (absmax pinned 3.9e-3 vs 1.57e-2):
//   weff = w_vec1 @ w_edge;  A = |weff| @ w_sca[:,:64]^T;  B = w_vec2 @ weff
//   out_sca = un*A + etype_row + gauss_window(d)
//   output_vec = (sigmoid(out_sca@Wg^T + b) * B)^2 * un^2
// ---------------------------------------------------------------------------
__global__ __launch_bounds__(TPB, 4) void edge_kernel(
    const int* __restrict__ idxA,     // [E]
    const int* __restrict__ idxB,     // [E]
    const float* __restrict__ feat,   // [E,5]
    const float* __restrict__ pos,    // [N,3]
    const float* __restrict__ w_edge, // [64]
    const float* __restrict__ w_vec1, // [64,64]
    const float* __restrict__ w_vec2, // [16,64]
    const float* __restrict__ w_sca,  // [16,320]
    const float* __restrict__ w_gate, // [16,16]
    const float* __restrict__ b_gate, // [16]
    float* __restrict__ out,
    int E)
{
    __shared__ __align__(16) float wg[252 * GP];   // gauss slice (+1 pad row)
    __shared__ __align__(16) float wt5[5 * GP];    // etype rows
    __shared__ __align__(16) float weff[64];
    __shared__ __align__(16) float As[16], Bs[16];
    __shared__ __align__(16) float sOut[4][64 * GP];

    const int tid = threadIdx.x;
    const int nchunk = (E + CHUNK - 1) / CHUNK;

    // ---- stage-0 prefetch: chunk c0's idx/feat, issued before everything ----
    const int c0 = blockIdx.x;
    {
        // nothing: c0 < NBLK <= could exceed nchunk only for tiny E; loop guards.
    }
    int eC = c0 * CHUNK + tid;
    int ecC = (eC < E) ? eC : (E - 1);
    int naC = __builtin_nontemporal_load(idxA + ecC);
    int nbC = __builtin_nontemporal_load(idxB + ecC);
    float fC[4];
    #pragma unroll
    for (int t = 0; t < 4; ++t)
        fC[t] = __builtin_nontemporal_load(feat + ecC * 5 + 1 + t);

    // ---- prologue: staging via independent float4 loads (1 round trip) ----
    #pragma unroll
    for (int k = 0; k < 4; ++k) {
        const int j4 = tid + k * TPB;          // float4 index over 16 heads x 63
        if (j4 < 16 * 63) {
            const int o  = j4 / 63;            // magic-mul
            const int k4 = j4 - o * 63;
            const f4 v = *(const f4*)(w_sca + o * W_SCA_COLS + DIM_HID + 4 * k4);
            wg[(4*k4 + 0) * GP + o] = v.x;     // row g=251 written (pad), never read
            wg[(4*k4 + 1) * GP + o] = v.y;
            wg[(4*k4 + 2) * GP + o] = v.z;
            wg[(4*k4 + 3) * GP + o] = v.w;
        }
    }
    if (tid < 80) {
        int t = tid >> 4, o = tid & 15;
        wt5[t * GP + o] = w_sca[o * W_SCA_COLS + DIM_HID + NUM_GAUSS + t];
    }
    if (tid < 64) {
        const float4* wrow = (const float4*)(w_vec1 + tid * 64);
        float s = 0.f;
        #pragma unroll
        for (int c4 = 0; c4 < 16; ++c4) {
            float4 v = wrow[c4];
            s += v.x * w_edge[c4*4+0] + v.y * w_edge[c4*4+1]
               + v.z * w_edge[c4*4+2] + v.w * w_edge[c4*4+3];
        }
        weff[tid] = s;
    }
    __syncthreads();
    if (tid < 16) {
        const float4* srow = (const float4*)(w_sca + tid * W_SCA_COLS);
        const float4* vrow = (const float4*)(w_vec2 + tid * 64);
        float a2 = 0.f, b2 = 0.f;
        #pragma unroll
        for (int k4 = 0; k4 < 16; ++k4) {
            float4 sv = srow[k4];
            float4 vv = vrow[k4];
            float4 wv = *(const float4*)&weff[k4 * 4];
            a2 += fabsf(wv.x)*sv.x + fabsf(wv.y)*sv.y + fabsf(wv.z)*sv.z + fabsf(wv.w)*sv.w;
            b2 += wv.x*vv.x + wv.y*vv.y + wv.z*vv.z + wv.w*vv.w;
        }
        As[tid] = a2;
        Bs[tid] = b2;
    }
    __syncthreads();

    // ---- pipeline priming: pos(c0) gather + stage-1 idx/feat(c0+NBLK) ----
    F3 paC, pbC;
    __builtin_memcpy(&paC, pos + naC * 3, 12);
    __builtin_memcpy(&pbC, pos + nbC * 3, 12);

    int eN = (c0 + NBLK) * CHUNK + tid;
    int ecN = (eN < E) ? eN : (E - 1);
    int naN = __builtin_nontemporal_load(idxA + ecN);
    int nbN = __builtin_nontemporal_load(idxB + ecN);
    float fN[4];
    #pragma unroll
    for (int t = 0; t < 4; ++t)
        fN[t] = __builtin_nontemporal_load(feat + ecN * 5 + 1 + t);

    const int wv = tid >> 6, l = tid & 63;
    float* sw = sOut[wv];
    const float NL2E = -1.44269504088896340736f;
    const float C2 = -312.5f * 1.44269504088896340736f;    // coeff * log2(e)

    for (int c = c0; c < nchunk; c += NBLK) {
        // ---- A: body of current chunk (pos in flight since last iter) ----
        const float vx = paC.x - pbC.x, vy = paC.y - pbC.y, vz = paC.z - pbC.z;
        const float d  = sqrtf(vx*vx + vy*vy + vz*vz);
        const float un = d * __builtin_amdgcn_rcpf(d + 1e-7f);
        const float u2 = un * un;
        const int ti = (int)(fC[0] + 2.f*fC[1] + 3.f*fC[2] + 4.f*fC[3] + 0.5f);

        int glo = (int)ceilf((d - RAD) * 25.f);
        glo = glo < 0 ? 0 : (glo > NUM_GAUSS - NW ? NUM_GAUSS - NW : glo);
        const float x0 = d - (float)glo * 0.04f;

        float acc[16];
        {
            const float4* ar  = (const float4*)As;
            const float4* t0r = (const float4*)&wt5[ti * GP];
            #pragma unroll
            for (int qq = 0; qq < 4; ++qq) {
                const float4 av = ar[qq];
                const float4 tv = t0r[qq];
                acc[4*qq+0] = fmaf(un, av.x, tv.x);
                acc[4*qq+1] = fmaf(un, av.y, tv.y);
                acc[4*qq+2] = fmaf(un, av.z, tv.z);
                acc[4*qq+3] = fmaf(un, av.w, tv.w);
            }
        }
        {
            const float* base = &wg[glo * GP];
            #pragma unroll
            for (int i = 0; i < NW; ++i) {
                const float t = x0 - (float)i * 0.04f;
                const float w = exp2f(C2 * t * t);
                const float4* row = (const float4*)(base + i * GP);
                #pragma unroll
                for (int qq = 0; qq < 4; ++qq) {
                    const float4 v = row[qq];
                    acc[4*qq+0] = fmaf(w, v.x, acc[4*qq+0]);
                    acc[4*qq+1] = fmaf(w, v.y, acc[4*qq+1]);
                    acc[4*qq+2] = fmaf(w, v.z, acc[4*qq+2]);
                    acc[4*qq+3] = fmaf(w, v.w, acc[4*qq+3]);
                }
            }
        }

        // ---- B: prefetch pos(next) (idx arrived last iter) + idx(next2) ----
        F3 paN, pbN;
        __builtin_memcpy(&paN, pos + naN * 3, 12);
        __builtin_memcpy(&pbN, pos + nbN * 3, 12);
        int e2 = (c + 2 * NBLK) * CHUNK + tid;
        int ec2 = (e2 < E) ? e2 : (E - 1);
        int na2 = __builtin_nontemporal_load(idxA + ec2);
        int nb2 = __builtin_nontemporal_load(idxB + ec2);
        float f2v[4];
        #pragma unroll
        for (int t = 0; t < 4; ++t)
            f2v[t] = __builtin_nontemporal_load(feat + ec2 * 5 + 1 + t);

        // ---- C: transpose-store out_sca, gate, store output_vec ----
        const int wbase = c * CHUNK + wv * 64;
        #pragma unroll
        for (int qq = 0; qq < 4; ++qq)
            *(float4*)&sw[l * GP + 4*qq] =
                make_float4(acc[4*qq], acc[4*qq+1], acc[4*qq+2], acc[4*qq+3]);
        __builtin_amdgcn_wave_barrier();
        #pragma unroll
        for (int s = 0; s < 4; ++s) {
            const int r = s * 16 + (l >> 2);
            const int cc = (l & 3) * 4;
            const f4 v = *(const f4*)&sw[r * GP + cc];
            if (wbase + r < E)
                __builtin_nontemporal_store(v, (f4*)(out + (size_t)(wbase + r) * 16 + cc));
        }
        __builtin_amdgcn_wave_barrier();

        #pragma unroll
        for (int oq = 0; oq < 16; oq += 4) {
            float ov[4];
            #pragma unroll
            for (int oi = 0; oi < 4; ++oi) {
                const int o = oq + oi;
                float x = b_gate[o];
                #pragma unroll
                for (int p = 0; p < 16; ++p) x = fmaf(acc[p], w_gate[o * 16 + p], x);
                const float gate = __builtin_amdgcn_rcpf(1.0f + exp2f(NL2E * x));
                const float gv = gate * Bs[o];
                ov[oi] = gv * gv * u2;
            }
            *(float4*)&sw[l * GP + oq] = make_float4(ov[0], ov[1], ov[2], ov[3]);
        }
        __builtin_amdgcn_wave_barrier();
        float* outv = out + (size_t)E * 16;
        #pragma unroll
        for (int s = 0; s < 4; ++s) {
            const int r = s * 16 + (l >> 2);
            const int cc = (l & 3) * 4;
            const f4 v = *(const f4*)&sw[r * GP + cc];
            if (wbase + r < E)
                __builtin_nontemporal_store(v, (f4*)(outv + (size_t)(wbase + r) * 16 + cc));
        }
        __builtin_amdgcn_wave_barrier();

        // ---- rotate pipeline registers ----
        paC = paN; pbC = pbN;
        #pragma unroll
        for (int t = 0; t < 4; ++t) fC[t] = fN[t];
        naN = na2; nbN = nb2;
        #pragma unroll
        for (int t = 0; t < 4; ++t) fN[t] = f2v[t];
    }
}

extern "C" void kernel_launch(void* const* d_in, const int* in_sizes, int n_in,
                              void* d_out, int out_size, void* d_ws, size_t ws_size,
                              hipStream_t stream) {
    const int*   idx    = (const int*)d_in[0];    // [2,E]
    const float* feat   = (const float*)d_in[1];  // [E,5]
    const float* pos    = (const float*)d_in[2];  // [N,3]
    const float* w_edge = (const float*)d_in[3];  // [64,1]
    const float* w_vec1 = (const float*)d_in[4];  // [64,64]
    const float* w_vec2 = (const float*)d_in[5];  // [16,64]
    const float* w_sca  = (const float*)d_in[6];  // [16,320]
    const float* w_gate = (const float*)d_in[7];  // [16,16]
    const float* b_gate = (const float*)d_in[8];  // [16]
    float* out = (float*)d_out;

    const int E = in_sizes[0] / 2;
    const int nchunk = (E + CHUNK - 1) / CHUNK;
    const int nblk = nchunk < NBLK ? nchunk : NBLK;
    edge_kernel<<<nblk, TPB, 0, stream>>>(idx, idx + E, feat, pos,
                                          w_edge, w_vec1, w_vec2,
                                          w_sca, w_gate, b_gate, out, E);
}